// Round 4
// baseline (3804.380 us; speedup 1.0000x reference)
//
#include <hip/hip_runtime.h>

#define NTOK 49
#define CDIM 96
#define NH   3
#define HD   32

typedef unsigned int uint4v __attribute__((ext_vector_type(4)));

__device__ __forceinline__ unsigned short f2bf(float f) {
  union { float f; unsigned u; } v; v.f = f;
  unsigned r = v.u + 0x7FFFu + ((v.u >> 16) & 1u);   // RNE
  return (unsigned short)(r >> 16);
}
__device__ __forceinline__ float bf2f(unsigned short h) {
  union { unsigned u; float f; } v; v.u = ((unsigned)h) << 16;
  return v.f;
}
__device__ __forceinline__ float bflo(unsigned u) {
  union { unsigned x; float f; } v; v.x = u << 16; return v.f;
}
__device__ __forceinline__ float bfhi(unsigned u) {
  union { unsigned x; float f; } v; v.x = u & 0xFFFF0000u; return v.f;
}

// ---------------------------------------------------------------------------
// Prep kernel: fp32 weights in -> fused/transposed bf16 weights in d_ws.
//   [     0..27648)  W1cat_t [288][96] = [wq_sp | wk_sp | wv]^T
//   [ 27648..46080)  W2cat_t [192][96] = per-head [q|k] slices of wq,wk
//   [ 46080..55296)  W1b_t   [96][96]  = (w_ps @ Wp_top)^T
//   [ 55296..64512)  W2b_t   [96][96]  = (w_pc @ Wp_bot)^T
//   [ 64512..73728)  Wpb_t   [96][96]  = Wp_bot^T
//   float[96] @ byte 147456: bias_all = b_ps@Wp_top + b_pc@Wp_bot + b_proj
// ---------------------------------------------------------------------------
__global__ void prep_weights(const float* __restrict__ wq,
                             const float* __restrict__ wk,
                             const float* __restrict__ wv,
                             const float* __restrict__ wq_sp,
                             const float* __restrict__ wk_sp,
                             const float* __restrict__ w_ps,
                             const float* __restrict__ b_ps,
                             const float* __restrict__ w_pc,
                             const float* __restrict__ b_pc,
                             const float* __restrict__ w_proj,
                             const float* __restrict__ b_proj,
                             unsigned short* __restrict__ wsS,
                             float* __restrict__ wsB)
{
  const int g0 = blockIdx.x * blockDim.x + threadIdx.x;
  const int gs = gridDim.x * blockDim.x;
  const int TOT = 73728 + 96;
  for (int idx = g0; idx < TOT; idx += gs) {
    if (idx < 27648) {
      int o = idx / 96, i = idx % 96;
      float v;
      if (o < 96)       v = wq_sp[i*96 + o];
      else if (o < 192) v = wk_sp[i*96 + (o-96)];
      else              v = wv  [i*96 + (o-192)];
      wsS[idx] = f2bf(v);
    } else if (idx < 46080) {
      int j = idx - 27648, o = j / 96, i = j % 96;
      int h = o >> 6, cc = o & 63;
      wsS[idx] = f2bf((cc < 32) ? wq[i*96 + h*32 + cc] : wk[i*96 + h*32 + (cc-32)]);
    } else if (idx < 55296) {
      int j = idx - 46080, o = j / 96, i = j % 96;
      float a = 0.f;
      for (int k = 0; k < 96; ++k) a += w_ps[i*96+k] * w_proj[k*96+o];
      wsS[idx] = f2bf(a);
    } else if (idx < 64512) {
      int j = idx - 55296, o = j / 96, i = j % 96;
      float a = 0.f;
      for (int k = 0; k < 96; ++k) a += w_pc[i*96+k] * w_proj[(96+k)*96+o];
      wsS[idx] = f2bf(a);
    } else if (idx < 73728) {
      int j = idx - 64512, o = j / 96, i = j % 96;
      wsS[idx] = f2bf(w_proj[(96+i)*96 + o]);
    } else {
      int o = idx - 73728;
      float a = b_proj[o];
      for (int k = 0; k < 96; ++k) {
        a += b_ps[k] * w_proj[k*96+o];
        a += b_pc[k] * w_proj[(96+k)*96+o];
      }
      wsB[o] = a;
    }
  }
}

// ---------------------------------------------------------------------------
// Pure-VALU fused window kernel (round-3 structure, fp32 global I/O).
// LDS slots (bf16 shorts):
//   X  [49][96] @0      : input window (never overwritten)
//   V  [49][96] @4704   : v_inp
//   QS [49][96] @9408   : qs -> xc
//   KS [49][96] @14112  : ks -> gelu(conv1) -> out_p
//   Q  [49][96] @18816  : q (all heads) -> sp (per head, in place)
//   K  [49][96] @23520  : k (all heads)
//   SC 3136     @28224  : cattn [96][32] then scores/probs [49][64]
// ---------------------------------------------------------------------------
__global__ __launch_bounds__(256, 2) void winattn_valu(
    const float* __restrict__ x,
    const float* __restrict__ rpb,      // [169][3]
    const float* __restrict__ bq,
    const float* __restrict__ bk,
    const float* __restrict__ bv,
    const float* __restrict__ conv1w,   // [9][96]
    const float* __restrict__ conv2w,   // [9][96]
    const unsigned short* __restrict__ wcat1,    // [288][96] bf16
    const unsigned short* __restrict__ wcat2,    // [192][96] bf16
    const unsigned short* __restrict__ w1b,      // [96][96] bf16
    const unsigned short* __restrict__ w2b,      // [96][96] bf16
    const unsigned short* __restrict__ wpb,      // [96][96] bf16
    const float* __restrict__ bias_all,          // [96]
    float* __restrict__ out)
{
  __shared__ __align__(16) unsigned short sm[31360];   // 62720 B
  const int tid = threadIdx.x;
  const int blk = blockIdx.x;
  enum { X_O = 0, V_O = 4704, QS_O = 9408, KS_O = 14112,
         Q_O = 18816, K_O = 23520, SC_O = 28224 };
  const float SCALE = 0.17677669529663687f;

  // ---- load x (fp32 -> bf16 LDS) ----
  {
    const float* xg = x + (size_t)blk * 4704;
    for (int i = tid; i < 1176; i += 256) {          // 1176*4 = 4704 floats
      const float4 v = *(const float4*)&xg[i*4];
      union { unsigned short s[4]; uint2 u; } p;
      p.s[0] = f2bf(v.x); p.s[1] = f2bf(v.y); p.s[2] = f2bf(v.z); p.s[3] = f2bf(v.w);
      *(uint2*)&sm[X_O + i*4] = p.u;
    }
  }
  __syncthreads();

  // ---- B: [qs|ks|v] = x @ Wcat1 (+bv on v); weight row cached in regs ----
  for (int c = tid; c < 288; c += 256) {
    uint4v wr[12];
    #pragma unroll
    for (int i = 0; i < 12; ++i) wr[i] = *(const uint4v*)&wcat1[c*96 + i*8];
    const float bias = (c >= 192) ? bv[c-192] : 0.0f;
    const int dst = (c < 96) ? (QS_O + c) : (c < 192) ? (KS_O + c - 96) : (V_O + c - 192);
    for (int n = 0; n < NTOK; ++n) {
      float a = bias;
      #pragma unroll
      for (int k = 0; k < 12; ++k) {
        const uint4v ua = *(const uint4v*)&sm[X_O + n*96 + k*8];
        #pragma unroll
        for (int j = 0; j < 4; ++j)
          a += bflo(ua[j])*bflo(wr[k][j]) + bfhi(ua[j])*bfhi(wr[k][j]);
      }
      sm[dst + n*96] = f2bf(a);
    }
  }
  __syncthreads();

  // ---- C: L2-normalize qs, ks along tokens (per channel) ----
  if (tid < 192) {
    const int base = (tid < 96) ? QS_O : KS_O;
    const int c    = (tid < 96) ? tid : tid - 96;
    float ss = 0.f;
    for (int n = 0; n < NTOK; ++n) { float v = bf2f(sm[base + n*96 + c]); ss += v*v; }
    const float rn = 1.0f / fmaxf(sqrtf(ss), 1e-12f);
    for (int n = 0; n < NTOK; ++n)
      sm[base + n*96 + c] = f2bf(bf2f(sm[base + n*96 + c]) * rn);
  }
  __syncthreads();

  // ---- D: cattn logits [96][32] -> SC ----
  for (int idx = tid; idx < 96*32; idx += 256) {
    const int dq = idx >> 5, e = idx & 31, h = dq >> 5;
    float a = 0.f;
    for (int n = 0; n < NTOK; ++n)
      a += bf2f(sm[KS_O + n*96 + dq]) * bf2f(sm[QS_O + n*96 + h*32 + e]);
    sm[SC_O + dq*32 + e] = f2bf(a * SCALE);
  }
  __syncthreads();

  // ---- E: softmax over e (96 rows of 32) ----
  if (tid < 96) {
    float m = -1e30f;
    for (int e = 0; e < 32; ++e) m = fmaxf(m, bf2f(sm[SC_O + tid*32 + e]));
    float s = 0.f;
    for (int e = 0; e < 32; ++e) s += __expf(bf2f(sm[SC_O + tid*32 + e]) - m);
    const float inv = 1.0f / s;
    for (int e = 0; e < 32; ++e)
      sm[SC_O + tid*32 + e] = f2bf(__expf(bf2f(sm[SC_O + tid*32 + e]) - m) * inv);
  }
  __syncthreads();

  // ---- F: xc[n][dq] = sum_e cattn[dq][e]*V[n][h*32+e] -> QS (qs dead) ----
  for (int idx = tid; idx < NTOK*96; idx += 256) {
    const int n = idx / 96, dq = idx % 96, h = dq >> 5;
    float a = 0.f;
    for (int e = 0; e < 32; ++e)
      a += bf2f(sm[SC_O + dq*32 + e]) * bf2f(sm[V_O + n*96 + h*32 + e]);
    sm[QS_O + n*96 + dq] = f2bf(a);
  }
  // ---- G: conv1 + exact GELU -> KS (ks dead; disjoint from F) ----
  for (int idx = tid; idx < NTOK*96; idx += 256) {
    const int n = idx / 96, c = idx % 96, y = n / 7, xx = n % 7;
    float a = 0.f;
    #pragma unroll
    for (int dy = -1; dy <= 1; ++dy) {
      const int yy = y + dy;
      if (yy < 0 || yy >= 7) continue;
      #pragma unroll
      for (int dx = -1; dx <= 1; ++dx) {
        const int x2 = xx + dx;
        if (x2 < 0 || x2 >= 7) continue;
        a += bf2f(sm[V_O + (yy*7+x2)*96 + c]) * conv1w[((dy+1)*3+(dx+1))*96 + c];
      }
    }
    a = 0.5f * a * (1.0f + erff(a * 0.70710678118654752f));
    sm[KS_O + idx] = f2bf(a);
  }
  __syncthreads();

  // ---- H: conv2 -> regs -> KS ----
  {
    float ov[19];
    #pragma unroll
    for (int it = 0; it < 19; ++it) {
      const int e = tid + it*256;
      float a = 0.f;
      if (e < 4704) {
        const int n = e / 96, c = e % 96, y = n / 7, xx = n % 7;
        #pragma unroll
        for (int dy = -1; dy <= 1; ++dy) {
          const int yy = y + dy;
          if (yy < 0 || yy >= 7) continue;
          #pragma unroll
          for (int dx = -1; dx <= 1; ++dx) {
            const int x2 = xx + dx;
            if (x2 < 0 || x2 >= 7) continue;
            a += bf2f(sm[KS_O + (yy*7+x2)*96 + c]) * conv2w[((dy+1)*3+(dx+1))*96 + c];
          }
        }
      }
      ov[it] = a;
    }
    __syncthreads();
    #pragma unroll
    for (int it = 0; it < 19; ++it) {
      const int e = tid + it*256;
      if (e < 4704) sm[KS_O + e] = f2bf(ov[it]);
    }
  }
  __syncthreads();

  // ---- I: q,k = x @ Wcat2 (+bq,bk) -> Q,K slots ----
  if (tid < 192) {
    const int c = tid, h = c >> 6, cc = c & 63;
    uint4v wr[12];
    #pragma unroll
    for (int i = 0; i < 12; ++i) wr[i] = *(const uint4v*)&wcat2[c*96 + i*8];
    const float bias = (cc < 32) ? bq[h*32 + cc] : bk[h*32 + cc - 32];
    const int dst = (cc < 32) ? (Q_O + h*32 + cc) : (K_O + h*32 + cc - 32);
    for (int n = 0; n < NTOK; ++n) {
      float a = bias;
      #pragma unroll
      for (int k = 0; k < 12; ++k) {
        const uint4v ua = *(const uint4v*)&sm[X_O + n*96 + k*8];
        #pragma unroll
        for (int j = 0; j < 4; ++j)
          a += bflo(ua[j])*bflo(wr[k][j]) + bfhi(ua[j])*bfhi(wr[k][j]);
      }
      sm[dst + n*96] = f2bf(a);
    }
  }
  __syncthreads();

  // ---- J: spatial attention per head ----
  for (int h = 0; h < NH; ++h) {
    for (int idx = tid; idx < NTOK*NTOK; idx += 256) {
      const int n = idx / 49, m2 = idx % 49;
      float a = 0.f;
      for (int j = 0; j < 32; ++j)
        a += bf2f(sm[Q_O + n*96 + h*32 + j]) * bf2f(sm[K_O + m2*96 + h*32 + j]);
      const int ridx = (n/7 - m2/7 + 6)*13 + (n%7 - m2%7 + 6);
      sm[SC_O + n*64 + m2] = f2bf(a * SCALE + rpb[ridx*NH + h]);
    }
    __syncthreads();
    if (tid < NTOK) {
      float m = -1e30f;
      for (int j = 0; j < NTOK; ++j) m = fmaxf(m, bf2f(sm[SC_O + tid*64 + j]));
      float s = 0.f;
      for (int j = 0; j < NTOK; ++j) s += __expf(bf2f(sm[SC_O + tid*64 + j]) - m);
      const float inv = 1.0f / s;
      for (int j = 0; j < NTOK; ++j)
        sm[SC_O + tid*64 + j] = f2bf(__expf(bf2f(sm[SC_O + tid*64 + j]) - m) * inv);
    }
    __syncthreads();
    for (int idx = tid; idx < NTOK*32; idx += 256) {
      const int n = idx / 32, d = idx % 32;
      float a = 0.f;
      for (int m2 = 0; m2 < NTOK; ++m2)
        a += bf2f(sm[SC_O + n*64 + m2]) * bf2f(sm[V_O + m2*96 + h*32 + d]);
      sm[Q_O + n*96 + h*32 + d] = f2bf(a);   // sp_h overwrites q_h (safe: q_h dead)
    }
    __syncthreads();
  }

  // ---- K: out = sp@W1b + xc@W2b + outp@Wpb + bias_all (fp32 store) ----
  if (tid < 192) {
    const int co = tid % 96, half = tid / 96;
    const int n0 = half ? 25 : 0;
    float acc[25];
    #pragma unroll
    for (int i = 0; i < 25; ++i) acc[i] = 0.f;
    const unsigned short* Ws[3] = { w1b, w2b, wpb };
    const int Ao[3] = { Q_O, QS_O, KS_O };
    for (int s = 0; s < 3; ++s) {
      uint4v wr[12];
      #pragma unroll
      for (int i = 0; i < 12; ++i) wr[i] = *(const uint4v*)&Ws[s][co*96 + i*8];
      #pragma unroll
      for (int i = 0; i < 25; ++i) {
        const int n = n0 + i;
        if (n < NTOK) {
          float a = 0.f;
          #pragma unroll
          for (int k = 0; k < 12; ++k) {
            const uint4v ua = *(const uint4v*)&sm[Ao[s] + n*96 + k*8];
            #pragma unroll
            for (int j = 0; j < 4; ++j)
              a += bflo(ua[j])*bflo(wr[k][j]) + bfhi(ua[j])*bfhi(wr[k][j]);
          }
          acc[i] += a;
        }
      }
    }
    float* og = out + (size_t)blk * 4704;
    const float b = bias_all[co];
    #pragma unroll
    for (int i = 0; i < 25; ++i) {
      const int n = n0 + i;
      if (n < NTOK) og[n*96 + co] = acc[i] + b;
    }
  }
}

extern "C" void kernel_launch(void* const* d_in, const int* in_sizes, int n_in,
                              void* d_out, int out_size, void* d_ws, size_t ws_size,
                              hipStream_t stream)
{
  const float* x      = (const float*)d_in[0];
  const float* rpbt   = (const float*)d_in[1];
  const float* wq     = (const float*)d_in[2];
  const float* bq     = (const float*)d_in[3];
  const float* wk     = (const float*)d_in[4];
  const float* bk     = (const float*)d_in[5];
  const float* wv     = (const float*)d_in[6];
  const float* bv     = (const float*)d_in[7];
  const float* w_ps   = (const float*)d_in[8];
  const float* b_ps   = (const float*)d_in[9];
  const float* wq_sp  = (const float*)d_in[10];
  const float* wk_sp  = (const float*)d_in[11];
  const float* w_pc   = (const float*)d_in[12];
  const float* b_pc   = (const float*)d_in[13];
  const float* conv1  = (const float*)d_in[14];
  const float* conv2  = (const float*)d_in[15];
  const float* w_proj = (const float*)d_in[16];
  const float* b_proj = (const float*)d_in[17];

  unsigned short* wsS = (unsigned short*)d_ws;
  float* wsB = (float*)((char*)d_ws + (size_t)2*73728);

  prep_weights<<<80, 256, 0, stream>>>(wq, wk, wv, wq_sp, wk_sp, w_ps, b_ps,
                                       w_pc, b_pc, w_proj, b_proj, wsS, wsB);

  const int nblk = in_sizes[0] / (NTOK*CDIM);   // 8192 windows
  winattn_valu<<<nblk, 256, 0, stream>>>(x, rpbt, bq, bk, bv, conv1, conv2,
      wsS, wsS + 27648, wsS + 46080, wsS + 55296, wsS + 64512, wsB,
      (float*)d_out);
}